// Round 10
// baseline (107.184 us; speedup 1.0000x reference)
//
#include <hip/hip_runtime.h>

#define D 256
#define NV 512
#define NT 512
#define KCAT 1536          // 6 concatenated K=256 segments (split-bf16 GEMM)
#define EPS 1e-8f
#define HALF_EPS 5e-9f
#define LN2 0.69314718055994531f

// Taylor of lgamma at 2.5 (row_stats deg-6 path)
#define C0 0.28468287047291920f
#define C1 0.70315664064524320f
#define C2 0.24517887805011740f
#define C3 (-0.03936734194028790f)
#define C4 0.00932941036738560f
#define C5 (-0.00261463332905590f)
#define C6 0.00080356830356760f
// Chebyshev-economized quadratic on s in [-1/2,1/2]
#define C0E 0.28460998445f
#define C1E 0.69577526404f
#define C2E 0.24751123064f

typedef float f32x4 __attribute__((ext_vector_type(4)));
typedef short s16x8 __attribute__((ext_vector_type(8)));
typedef unsigned short u16;

__device__ __forceinline__ float rcpf(float x) { return __builtin_amdgcn_rcpf(x); }

__device__ __forceinline__ u16 f2bf(float f) {   // RNE f32 -> bf16 bits
    unsigned int u = __float_as_uint(f);
    return (u16)((u + 0x7FFFu + ((u >> 16) & 1u)) >> 16);
}
__device__ __forceinline__ float bf2f(u16 b) {
    return __uint_as_float(((unsigned int)b) << 16);
}

__device__ __forceinline__ float stirling_lgamma(float y) { // y >= 4
    float r = rcpf(y), r2 = r * r;
    float ln = LN2 * __log2f(y);
    return (y - 0.5f) * ln - y + 0.91893853320467f
         + r * (0.08333333333f - 0.00277777778f * r2);
}

__device__ __forceinline__ float stirling_digamma(float y) { // y >= 4
    float r = rcpf(y), r2 = r * r;
    return LN2 * __log2f(y) - 0.5f * r - r2 * (0.08333333333f - 0.00833333333f * r2);
}

// One block per row. Scalars float4 [S, A, dgS, Q]; packed split-bf16 GEMM rows.
// A = 0.5*(lgamma(S') - sum lgamma(x')) + 0.25*sum(x'*psi);  Q = sum (0.5x')^2.
// psi_mod = psi(x') - C2E*x' folds the v.t cross term into the dot GEMM.
// t-rows -> Acat [x_hi|x_hi|x_lo|p_hi|p_hi|p_lo]; v-rows -> Bcat [p_hi|p_lo|p_hi|x_hi|x_lo|x_hi]
__global__ __launch_bounds__(256) void row_stats(
    const float* __restrict__ va, const float* __restrict__ ta,
    u16* __restrict__ Acat, u16* __restrict__ Bcat,
    float* __restrict__ rv, float* __restrict__ rt)
{
    int r = blockIdx.x;
    bool isV = (r < NV);
    int rr = isV ? r : r - NV;
    const float* row = (isV ? va : ta) + rr * D;
    float* sc = (isV ? rv : rt) + rr * 4;
    u16* cat = (isV ? Bcat : Acat) + rr * KCAT;

    int d = threadIdx.x;
    float raw = row[d];
    float x = raw + EPS;

    float y = x + 4.0f;
    float ry = rcpf(y), ry2 = ry * ry;
    float psi = LN2 * __log2f(y) - 0.5f * ry - ry2 * (0.08333333333f - 0.00833333333f * ry2);
    psi -= rcpf(x) + rcpf(x + 1.0f) + rcpf(x + 2.0f) + rcpf(x + 3.0f);

    float s = x - 0.5f;
    float q6 = fmaf(C6, s, C5);
    q6 = fmaf(q6, s, C4); q6 = fmaf(q6, s, C3); q6 = fmaf(q6, s, C2); q6 = fmaf(q6, s, C1);
    float g = fmaf(q6, s, C0) - LN2 * __log2f(x * (x + 1.0f));

    // split-bf16 operands
    float pm = psi - C2E * x;
    u16 xh = f2bf(x);  u16 xl = f2bf(x - bf2f(xh));
    u16 ph = f2bf(pm); u16 pl = f2bf(pm - bf2f(ph));
    if (isV) {  // B_cat
        cat[d] = ph; cat[d+256] = pl; cat[d+512] = ph;
        cat[d+768] = xh; cat[d+1024] = xl; cat[d+1280] = xh;
    } else {    // A_cat
        cat[d] = xh; cat[d+256] = xh; cat[d+512] = xl;
        cat[d+768] = ph; cat[d+1024] = ph; cat[d+1280] = pl;
    }

    float vh = fmaf(0.5f, raw, HALF_EPS);
    float S = raw, G = g, P = x * psi, Q = vh * vh;
    #pragma unroll
    for (int off = 32; off > 0; off >>= 1) {
        S += __shfl_down(S, off, 64);
        G += __shfl_down(G, off, 64);
        P += __shfl_down(P, off, 64);
        Q += __shfl_down(Q, off, 64);
    }
    __shared__ float red[4][4];
    int wid = d >> 6, lane = d & 63;
    if (lane == 0) { red[0][wid] = S; red[1][wid] = G; red[2][wid] = P; red[3][wid] = Q; }
    __syncthreads();
    if (d == 0) {
        float S4 = red[0][0] + red[0][1] + red[0][2] + red[0][3];
        float G4 = red[1][0] + red[1][1] + red[1][2] + red[1][3];
        float P4 = red[2][0] + red[2][1] + red[2][2] + red[2][3];
        float Q4 = red[3][0] + red[3][1] + red[3][2] + red[3][3];
        float Se = S4 + 256.0f * EPS;
        float A = 0.5f * (stirling_lgamma(Se) - G4) + 0.25f * P4;
        *(float4*)sc = make_float4(S4, A, stirling_digamma(Se), Q4);
    }
}

// 16x16 tile, 256 thr (4 waves). NO LDS STAGING: v/t rows are read directly
// from global (L2-resident, per wave-iter 16 v-lines + 4 t-broadcasts).
// MFMA computes the fused bilinear term W (K-split 384/wave, 4 KB LDS reduce);
// VALU computes sum lgamma(m) via quadratic power-sums + one log per 4 elems.
// One barrier total.
__global__ __launch_bounds__(256, 4) void jsd_pairs(
    const float* __restrict__ va, const float* __restrict__ ta,
    const u16* __restrict__ Acat, const u16* __restrict__ Bcat,
    const float* __restrict__ rv, const float* __restrict__ rt,
    float* __restrict__ out)
{
    __shared__ float red[4 * 256];

    const int tid = threadIdx.x;
    const int j0 = blockIdx.x * 16;      // v rows (output cols)
    const int i0 = blockIdx.y * 16;      // t rows (output rows)
    const int w = tid >> 6, l = tid & 63;

    // ---- MFMA part: this block's 16x16 W-tile, K split across 4 waves ----
    {
        f32x4 acc = {0.0f, 0.0f, 0.0f, 0.0f};
        const u16* Ap = Acat + (i0 + (l & 15)) * KCAT + w * 384 + ((l >> 4) << 3);
        const u16* Bp = Bcat + (j0 + (l & 15)) * KCAT + w * 384 + ((l >> 4) << 3);
        #pragma unroll
        for (int st = 0; st < 12; ++st) {
            s16x8 a = *(const s16x8*)(Ap + (st << 5));
            s16x8 b = *(const s16x8*)(Bp + (st << 5));
            acc = __builtin_amdgcn_mfma_f32_16x16x32_bf16(a, b, acc, 0, 0, 0);
        }
        int base = w * 256 + ((l >> 4) << 6) + (l & 15);   // row=(l>>4)*4+r, col=l&15
        red[base]      = acc[0];
        red[base + 16] = acc[1];
        red[base + 32] = acc[2];
        red[base + 48] = acc[3];
    }
    __syncthreads();                     // publish red[]; only barrier

    const int tj = tid & 15;
    const int ti = tid >> 4;
    const float* vrow = va + (j0 + tj) * D;
    const float* trow = ta + (i0 + ti) * D;

    float acc0 = 0.0f, acc1 = 0.0f, acc2 = 0.0f, acc3 = 0.0f;

    #define CITER(c, ACC) {                                                   \
        float4 v4 = *(const float4*)(vrow + ((c) << 2));                      \
        float4 t4 = *(const float4*)(trow + ((c) << 2));                      \
        float m0 = fmaf(0.5f, v4.x + t4.x, EPS);                              \
        float m1 = fmaf(0.5f, v4.y + t4.y, EPS);                              \
        float m2 = fmaf(0.5f, v4.z + t4.z, EPS);                              \
        float m3 = fmaf(0.5f, v4.w + t4.w, EPS);                              \
        float w0 = fmaf(m0, m0, m0), w1 = fmaf(m1, m1, m1);                   \
        float w2 = fmaf(m2, m2, m2), w3 = fmaf(m3, m3, m3);                   \
        ACC += __log2f((w0 * w1) * (w2 * w3)); }

    #pragma unroll 2
    for (int c = 0; c < 64; c += 4) {
        CITER(c + 0, acc0) CITER(c + 1, acc1) CITER(c + 2, acc2) CITER(c + 3, acc3)
    }

    const int idx = ti * 16 + tj;
    float W = red[idx] + red[256 + idx] + red[512 + idx] + red[768 + idx];

    const int j = j0 + tj, i = i0 + ti;
    float4 RJ = *(const float4*)(rv + j * 4);
    float4 RI = *(const float4*)(rt + i * 4);
    float Sv = RJ.x, Av = RJ.y, dgSv = RJ.z, Qv = RJ.w;
    float St = RI.x, At = RI.y, dgSt = RI.z, Qt = RI.w;

    float M1 = fmaf(0.5f, Sv + St, 256.0f * EPS);  // sum of m_d
    float S1 = M1 - 128.0f;                        // sum of s
    float quad = Qv + Qt - M1 + 64.0f;             // self part of sum s^2 (cross in W)
    float sumlg = fmaf(C1E, S1, 256.0f * C0E) + C2E * quad
                - LN2 * ((acc0 + acc1) + (acc2 + acc3));

    float jsd = sumlg - stirling_lgamma(M1) + Av + At
              - 0.25f * W
              + 0.25f * (Sv - St) * (dgSt - dgSv);

    out[i * 512 + j] = 1.0f - jsd;
}

extern "C" void kernel_launch(void* const* d_in, const int* in_sizes, int n_in,
                              void* d_out, int out_size, void* d_ws, size_t ws_size,
                              hipStream_t stream) {
    const float* va = (const float*)d_in[0];
    const float* ta = (const float*)d_in[1];
    float* ws  = (float*)d_ws;
    float* rv  = ws;                                   // 512*4 f32
    float* rt  = ws + NV * 4;                          // 512*4 f32
    u16*   Acat = (u16*)((char*)d_ws + 16384);         // 512*1536 bf16
    u16*   Bcat = (u16*)((char*)d_ws + 16384 + NV * KCAT * 2);
    float* out = (float*)d_out;

    row_stats<<<NV + NT, 256, 0, stream>>>(va, ta, Acat, Bcat, rv, rt);
    jsd_pairs<<<dim3(32, 32), 256, 0, stream>>>(va, ta, Acat, Bcat, rv, rt, out);
}

// Round 11
// 71.445 us; speedup vs baseline: 1.5002x; 1.5002x over previous
//
#include <hip/hip_runtime.h>

#define D 256
#define NV 512
#define NT 512
#define KCAT 1536          // 6 concatenated K=256 segments (split-bf16 GEMM)
#define EPS 1e-8f
#define HALF_EPS 5e-9f
#define LN2 0.69314718055994531f

// Taylor of lgamma at 2.5 (row_stats deg-6 path)
#define C0 0.28468287047291920f
#define C1 0.70315664064524320f
#define C2 0.24517887805011740f
#define C3 (-0.03936734194028790f)
#define C4 0.00932941036738560f
#define C5 (-0.00261463332905590f)
#define C6 0.00080356830356760f
// Chebyshev-economized quadratic on s in [-1/2,1/2]
#define C0E 0.28460998445f
#define C1E 0.69577526404f
#define C2E 0.24751123064f

#define LSTRIDE 68

typedef float f32x4 __attribute__((ext_vector_type(4)));
typedef short s16x8 __attribute__((ext_vector_type(8)));
typedef unsigned short u16;

__device__ __forceinline__ float rcpf(float x) { return __builtin_amdgcn_rcpf(x); }

__device__ __forceinline__ u16 f2bf(float f) {   // RNE f32 -> bf16 bits
    unsigned int u = __float_as_uint(f);
    return (u16)((u + 0x7FFFu + ((u >> 16) & 1u)) >> 16);
}
__device__ __forceinline__ float bf2f(u16 b) {
    return __uint_as_float(((unsigned int)b) << 16);
}

__device__ __forceinline__ float stirling_lgamma(float y) { // y >= 4
    float r = rcpf(y), r2 = r * r;
    float ln = LN2 * __log2f(y);
    return (y - 0.5f) * ln - y + 0.91893853320467f
         + r * (0.08333333333f - 0.00277777778f * r2);
}

__device__ __forceinline__ float stirling_digamma(float y) { // y >= 4
    float r = rcpf(y), r2 = r * r;
    return LN2 * __log2f(y) - 0.5f * r - r2 * (0.08333333333f - 0.00833333333f * r2);
}

// Fragment-order transposed GEMM operand layout:
// element (global k, row) lives at ((k>>3)*512 + row)*8 + (k&7).
// MFMA frag read (lane l): rows i0..i0+15 contiguous 256B per 16-lane group.
__device__ __forceinline__ int tidx(int s, int d, int rr) {
    return (((s << 5) + (d >> 3)) * 512 + rr) * 8 + (d & 7);
}

// One block per row. Scalars float4 [S, A, dgS, Q]; fragment-order split-bf16.
// A = 0.5*(lgamma(S') - sum lgamma(x')) + 0.25*sum(x'*psi);  Q = sum (0.5x')^2.
// psi_mod = psi(x') - C2E*x' folds the v.t cross term into the dot GEMM.
// t-rows -> Acat segs [x_hi|x_hi|x_lo|p_hi|p_hi|p_lo]; v-rows -> Bcat [p_hi|p_lo|p_hi|x_hi|x_lo|x_hi]
__global__ __launch_bounds__(256) void row_stats(
    const float* __restrict__ va, const float* __restrict__ ta,
    u16* __restrict__ AcatT, u16* __restrict__ BcatT,
    float* __restrict__ rv, float* __restrict__ rt)
{
    int r = blockIdx.x;
    bool isV = (r < NV);
    int rr = isV ? r : r - NV;
    const float* row = (isV ? va : ta) + rr * D;
    float* sc = (isV ? rv : rt) + rr * 4;
    u16* cat = isV ? BcatT : AcatT;

    int d = threadIdx.x;
    float raw = row[d];
    float x = raw + EPS;

    float y = x + 4.0f;
    float ry = rcpf(y), ry2 = ry * ry;
    float psi = LN2 * __log2f(y) - 0.5f * ry - ry2 * (0.08333333333f - 0.00833333333f * ry2);
    psi -= rcpf(x) + rcpf(x + 1.0f) + rcpf(x + 2.0f) + rcpf(x + 3.0f);

    float s = x - 0.5f;
    float q6 = fmaf(C6, s, C5);
    q6 = fmaf(q6, s, C4); q6 = fmaf(q6, s, C3); q6 = fmaf(q6, s, C2); q6 = fmaf(q6, s, C1);
    float g = fmaf(q6, s, C0) - LN2 * __log2f(x * (x + 1.0f));

    // split-bf16 operands
    float pm = psi - C2E * x;
    u16 xh = f2bf(x);  u16 xl = f2bf(x - bf2f(xh));
    u16 ph = f2bf(pm); u16 pl = f2bf(pm - bf2f(ph));
    if (isV) {  // B side
        cat[tidx(0,d,rr)] = ph; cat[tidx(1,d,rr)] = pl; cat[tidx(2,d,rr)] = ph;
        cat[tidx(3,d,rr)] = xh; cat[tidx(4,d,rr)] = xl; cat[tidx(5,d,rr)] = xh;
    } else {    // A side
        cat[tidx(0,d,rr)] = xh; cat[tidx(1,d,rr)] = xh; cat[tidx(2,d,rr)] = xl;
        cat[tidx(3,d,rr)] = ph; cat[tidx(4,d,rr)] = ph; cat[tidx(5,d,rr)] = pl;
    }

    float vh = fmaf(0.5f, raw, HALF_EPS);
    float S = raw, G = g, P = x * psi, Q = vh * vh;
    #pragma unroll
    for (int off = 32; off > 0; off >>= 1) {
        S += __shfl_down(S, off, 64);
        G += __shfl_down(G, off, 64);
        P += __shfl_down(P, off, 64);
        Q += __shfl_down(Q, off, 64);
    }
    __shared__ float red[4][4];
    int wid = d >> 6, lane = d & 63;
    if (lane == 0) { red[0][wid] = S; red[1][wid] = G; red[2][wid] = P; red[3][wid] = Q; }
    __syncthreads();
    if (d == 0) {
        float S4 = red[0][0] + red[0][1] + red[0][2] + red[0][3];
        float G4 = red[1][0] + red[1][1] + red[1][2] + red[1][3];
        float P4 = red[2][0] + red[2][1] + red[2][2] + red[2][3];
        float Q4 = red[3][0] + red[3][1] + red[3][2] + red[3][3];
        float Se = S4 + 256.0f * EPS;
        float A = 0.5f * (stirling_lgamma(Se) - G4) + 0.25f * P4;
        *(float4*)sc = make_float4(S4, A, stirling_digamma(Se), Q4);
    }
}

// 16x16 tile, 256 thr (4 waves). MFMA computes the fused bilinear W from
// fragment-order operands (coalesced 256B-per-16-lane reads), K split 384/wave.
// VALU computes sum lgamma(m) via quadratic power-sums + one log per 4 elems,
// over 4 width-64 LDS-staged phases with register prefetch of the next phase.
__global__ __launch_bounds__(256, 4) void jsd_pairs(
    const float* __restrict__ va, const float* __restrict__ ta,
    const u16* __restrict__ AcatT, const u16* __restrict__ BcatT,
    const float* __restrict__ rv, const float* __restrict__ rt,
    float* __restrict__ out)
{
    __shared__ float vs[16 * LSTRIDE];
    __shared__ float ts[16 * LSTRIDE];
    __shared__ float red[4 * 256];

    const int tid = threadIdx.x;
    const int j0 = blockIdx.x * 16;      // v rows (output cols)
    const int i0 = blockIdx.y * 16;      // t rows (output rows)
    const int w = tid >> 6, l = tid & 63;

    const int tj = tid & 15;
    const int ti = tid >> 4;

    // ---- issue phase-0 staging loads first ----
    float4 cv = *(const float4*)(va + (j0 + ti) * D + (tj << 2));
    float4 ct = *(const float4*)(ta + (i0 + ti) * D + (tj << 2));

    // ---- MFMA part: 16x16 W-tile, K split across 4 waves, coalesced frags ----
    {
        f32x4 acc = {0.0f, 0.0f, 0.0f, 0.0f};
        const u16* Ap = AcatT + (((w * 48 + (l >> 4)) * 512) + i0 + (l & 15)) * 8;
        const u16* Bp = BcatT + (((w * 48 + (l >> 4)) * 512) + j0 + (l & 15)) * 8;
        #pragma unroll
        for (int st = 0; st < 12; ++st) {
            s16x8 a = *(const s16x8*)(Ap + st * 16384);   // +4 chunks = 4*512*8
            s16x8 b = *(const s16x8*)(Bp + st * 16384);
            acc = __builtin_amdgcn_mfma_f32_16x16x32_bf16(a, b, acc, 0, 0, 0);
        }
        int base = w * 256 + ((l >> 4) << 6) + (l & 15);   // row=(l>>4)*4+r, col=l&15
        red[base]      = acc[0];
        red[base + 16] = acc[1];
        red[base + 32] = acc[2];
        red[base + 48] = acc[3];
    }

    const float* vp = vs + tj * LSTRIDE;
    const float* tp = ts + ti * LSTRIDE;
    const int ldst = ti * LSTRIDE + (tj << 2);

    float acc0 = 0.0f, acc1 = 0.0f, acc2 = 0.0f, acc3 = 0.0f;

    #define HALVE4(P) { P.x = fmaf(0.5f,P.x,HALF_EPS); P.y = fmaf(0.5f,P.y,HALF_EPS); \
                        P.z = fmaf(0.5f,P.z,HALF_EPS); P.w = fmaf(0.5f,P.w,HALF_EPS); }

    #define CITER(c, ACC) {                                                   \
        float4 v4 = *(const float4*)(vp + ((c) << 2));                        \
        float4 t4 = *(const float4*)(tp + ((c) << 2));                        \
        float m0 = v4.x + t4.x, m1 = v4.y + t4.y;                             \
        float m2 = v4.z + t4.z, m3 = v4.w + t4.w;                             \
        float w0 = fmaf(m0, m0, m0), w1 = fmaf(m1, m1, m1);                   \
        float w2 = fmaf(m2, m2, m2), w3 = fmaf(m3, m3, m3);                   \
        ACC += __log2f((w0 * w1) * (w2 * w3)); }

    #pragma unroll 1
    for (int h = 0; h < 4; ++h) {
        if (h) __syncthreads();          // previous phase's LDS reads done
        float4 sv = cv, st4 = ct;
        HALVE4(sv); HALVE4(st4);
        *(float4*)(vs + ldst) = sv;
        *(float4*)(ts + ldst) = st4;
        if (h < 3) {                     // prefetch next phase into regs
            int goff = ((h + 1) << 6) + (tj << 2);
            cv = *(const float4*)(va + (j0 + ti) * D + goff);
            ct = *(const float4*)(ta + (i0 + ti) * D + goff);
        }
        __syncthreads();
        CITER(0, acc0)  CITER(1, acc1)  CITER(2, acc2)  CITER(3, acc3)
        CITER(4, acc0)  CITER(5, acc1)  CITER(6, acc2)  CITER(7, acc3)
        CITER(8, acc0)  CITER(9, acc1)  CITER(10, acc2) CITER(11, acc3)
        CITER(12, acc0) CITER(13, acc1) CITER(14, acc2) CITER(15, acc3)
    }

    const int idx = ti * 16 + tj;
    float W = red[idx] + red[256 + idx] + red[512 + idx] + red[768 + idx];

    const int j = j0 + tj, i = i0 + ti;
    float4 RJ = *(const float4*)(rv + j * 4);
    float4 RI = *(const float4*)(rt + i * 4);
    float Sv = RJ.x, Av = RJ.y, dgSv = RJ.z, Qv = RJ.w;
    float St = RI.x, At = RI.y, dgSt = RI.z, Qt = RI.w;

    float M1 = fmaf(0.5f, Sv + St, 256.0f * EPS);  // sum of m_d
    float S1 = M1 - 128.0f;                        // sum of s
    float quad = Qv + Qt - M1 + 64.0f;             // self part of sum s^2 (cross in W)
    float sumlg = fmaf(C1E, S1, 256.0f * C0E) + C2E * quad
                - LN2 * ((acc0 + acc1) + (acc2 + acc3));

    float jsd = sumlg - stirling_lgamma(M1) + Av + At
              - 0.25f * W
              + 0.25f * (Sv - St) * (dgSt - dgSv);

    out[i * 512 + j] = 1.0f - jsd;
}

extern "C" void kernel_launch(void* const* d_in, const int* in_sizes, int n_in,
                              void* d_out, int out_size, void* d_ws, size_t ws_size,
                              hipStream_t stream) {
    const float* va = (const float*)d_in[0];
    const float* ta = (const float*)d_in[1];
    float* ws  = (float*)d_ws;
    float* rv  = ws;                                   // 512*4 f32
    float* rt  = ws + NV * 4;                          // 512*4 f32
    u16*   AcatT = (u16*)((char*)d_ws + 16384);        // 192 chunks x 512 rows x 8
    u16*   BcatT = (u16*)((char*)d_ws + 16384 + NV * KCAT * 2);
    float* out = (float*)d_out;

    row_stats<<<NV + NT, 256, 0, stream>>>(va, ta, AcatT, BcatT, rv, rt);
    jsd_pairs<<<dim3(32, 32), 256, 0, stream>>>(va, ta, AcatT, BcatT, rv, rt, out);
}